// Round 1
// baseline (1370.629 us; speedup 1.0000x reference)
//
#include <hip/hip_runtime.h>
#include <cstdint>
#include <cstddef>

// Problem constants (compile-time per reference)
#define BB 64
#define SS 1024
#define HH 1024
#define NSS 8

// scale i: size = 1024>>i, stride = size/2, n_i = 1024/stride - 1 = 2^(i+1)-1
// P rows padded per scale to multiple of 128: region = 64*(n_i+1) = 128*2^i rows
__device__ __constant__ int PBrow_c[8]    = {0,128,384,896,1920,3968,8064,16256};   // padded row base per scale
__device__ __constant__ int realbase_c[8] = {0,64,256,704,1664,3648,7680,15808};    // cumulative real rows
// total padded rows = 32640, total real rows = 32128

#define INV32 0.03125f   // 1/sqrt(H) = 1/sqrt(H*T)

__device__ __forceinline__ uint16_t f2bf(float f) {
  union { float f; uint32_t u; } v; v.f = f;
  uint32_t r = v.u + 0x7fffu + ((v.u >> 16) & 1u);   // RNE; inputs are finite/bounded
  return (uint16_t)(r >> 16);
}
__device__ __forceinline__ float bf_lo(uint32_t w) { return __uint_as_float(w << 16); }
__device__ __forceinline__ float bf_hi(uint32_t w) { return __uint_as_float(w & 0xffff0000u); }

// ---------------------------------------------------------------------------
// Skinny GEMM: out[64][1024] (+)= A[64][1024] @ W (+ bias + addb), split-K=4
// TRANSB=false: W indexed [k][n]; TRANSB=true: W indexed [n][k]
// out MUST be pre-zeroed (atomicAdd accumulation across k-splits).
// ---------------------------------------------------------------------------
template<bool TRANSB>
__global__ __launch_bounds__(256) void gemm64(
    const float* __restrict__ A, size_t a_stride,
    const float* __restrict__ W,
    const float* __restrict__ bias,
    const float* __restrict__ addb,
    float* __restrict__ out)
{
  __shared__ float As[64][68];   // [k][m], pad 68 keeps float4 16B-aligned
  __shared__ float Bs[64][68];   // [k][n]
  const int t  = threadIdx.x;
  const int nt = blockIdx.x;     // 16 n-tiles of 64
  const int ks = blockIdx.y;     // 4 k-splits of 256
  const int m0 = (t >> 4) << 2;
  const int n0 = (t & 15) << 2;
  float acc[4][4] = {};
  for (int kt = 0; kt < 4; ++kt) {
    const int k0 = ks * 256 + kt * 64;
    { // A tile 64x64 -> As[k][m]
      const int m  = t >> 2;
      const int kb = (t & 3) << 4;
      #pragma unroll
      for (int j = 0; j < 4; ++j) {
        const int k = kb + j * 4;
        const float4 v = *(const float4*)(A + (size_t)m * a_stride + k0 + k);
        As[k+0][m] = v.x; As[k+1][m] = v.y; As[k+2][m] = v.z; As[k+3][m] = v.w;
      }
    }
    if (!TRANSB) {
      const int k  = t >> 2;
      const int nb = (t & 3) << 4;
      #pragma unroll
      for (int j = 0; j < 4; ++j) {
        const int n = nb + j * 4;
        *(float4*)&Bs[k][n] = *(const float4*)(W + (size_t)(k0 + k) * HH + nt * 64 + n);
      }
    } else {
      const int n  = t >> 2;
      const int kb = (t & 3) << 4;
      #pragma unroll
      for (int j = 0; j < 4; ++j) {
        const int k = kb + j * 4;
        const float4 v = *(const float4*)(W + (size_t)(nt * 64 + n) * HH + k0 + k);
        Bs[k+0][n] = v.x; Bs[k+1][n] = v.y; Bs[k+2][n] = v.z; Bs[k+3][n] = v.w;
      }
    }
    __syncthreads();
    #pragma unroll 16
    for (int k = 0; k < 64; ++k) {
      const float4 av = *(const float4*)&As[k][m0];
      const float4 bv = *(const float4*)&Bs[k][n0];
      const float a[4] = {av.x, av.y, av.z, av.w};
      const float b[4] = {bv.x, bv.y, bv.z, bv.w};
      #pragma unroll
      for (int i2 = 0; i2 < 4; ++i2)
        #pragma unroll
        for (int j2 = 0; j2 < 4; ++j2)
          acc[i2][j2] += a[i2] * b[j2];
    }
    __syncthreads();
  }
  #pragma unroll
  for (int i2 = 0; i2 < 4; ++i2) {
    const int m = m0 + i2;
    #pragma unroll
    for (int j2 = 0; j2 < 4; ++j2) {
      const int n = nt * 64 + n0 + j2;
      float v = acc[i2][j2];
      if (ks == 0) {
        if (bias) v += bias[n];
        if (addb) v += addb[(size_t)m * HH + n];
      }
      atomicAdd(out + (size_t)m * HH + n, v);
    }
  }
}

// ---------------------------------------------------------------------------
// scale_importance = softmax(x_last @ Ws + bs) per batch  (tiny)
// ---------------------------------------------------------------------------
__global__ __launch_bounds__(256) void si_kernel(const float* __restrict__ x,
    const float* __restrict__ Ws, const float* __restrict__ bs,
    float* __restrict__ si)
{
  const int b = blockIdx.x, t = threadIdx.x;
  const int n = t & 7, kc = t >> 3;            // 32 k-chunks of 32
  const float* xl = x + ((size_t)b * SS + (SS - 1)) * HH;
  float p = 0.f;
  for (int kk = 0; kk < 32; ++kk) {
    const int k = kc * 32 + kk;
    p += xl[k] * Ws[k * NSS + n];
  }
  __shared__ float red[32][9];
  __shared__ float lg[8];
  red[kc][n] = p;
  __syncthreads();
  if (t < 8) {
    float s2 = bs[t];
    for (int c = 0; c < 32; ++c) s2 += red[c][t];
    lg[t] = s2;
  }
  __syncthreads();
  if (t == 0) {
    float mx = lg[0];
    #pragma unroll
    for (int j = 1; j < 8; ++j) mx = fmaxf(mx, lg[j]);
    float e[8]; float sm = 0.f;
    #pragma unroll
    for (int j = 0; j < 8; ++j) { e[j] = expf(lg[j] - mx); sm += e[j]; }
    const float inv = 1.0f / sm;
    #pragma unroll
    for (int j = 0; j < 8; ++j) si[b * NSS + j] = e[j] * inv;
  }
}

// ---------------------------------------------------------------------------
// score logits: attn[b][s] = (x[b,s,:] . qk[b,:]) * 1/32
// (q.bk constant over s -> cancels in softmax, exactly)
// ---------------------------------------------------------------------------
__global__ __launch_bounds__(256) void score_kernel(const float* __restrict__ x,
    const float* __restrict__ qk, float* __restrict__ attn)
{
  const int b = blockIdx.y, sc = blockIdx.x;   // 128 chunks of 8 s
  const int t = threadIdx.x;
  const int lane = t & 63, w = t >> 6;
  __shared__ float qks[HH];
  __shared__ float red[8][4];
  *(float4*)&qks[t * 4] = *(const float4*)&qk[b * HH + t * 4];
  __syncthreads();
  for (int ss = 0; ss < 8; ++ss) {
    const int s = sc * 8 + ss;
    const float4 xv = *(const float4*)&x[((size_t)b * SS + s) * HH + t * 4];
    const float4 qv = *(const float4*)&qks[t * 4];
    float p = xv.x * qv.x + xv.y * qv.y + xv.z * qv.z + xv.w * qv.w;
    #pragma unroll
    for (int off = 32; off > 0; off >>= 1) p += __shfl_down(p, off);
    if (lane == 0) red[ss][w] = p;
  }
  __syncthreads();
  if (t < 8) {
    const float v = (red[t][0] + red[t][1] + red[t][2] + red[t][3]) * INV32;
    attn[(size_t)b * SS + sc * 8 + t] = v;
  }
}

// softmax over S=1024, in place
__global__ __launch_bounds__(256) void softmax_s(float* __restrict__ attn)
{
  const int b = blockIdx.x, t = threadIdx.x;
  float* row = attn + (size_t)b * SS;
  float4 v = *(float4*)&row[t * 4];
  float mx = fmaxf(fmaxf(v.x, v.y), fmaxf(v.z, v.w));
  #pragma unroll
  for (int off = 32; off > 0; off >>= 1) mx = fmaxf(mx, __shfl_xor(mx, off));
  __shared__ float rm[4];
  __shared__ float rs[4];
  if ((t & 63) == 0) rm[t >> 6] = mx;
  __syncthreads();
  mx = fmaxf(fmaxf(rm[0], rm[1]), fmaxf(rm[2], rm[3]));
  const float e0 = expf(v.x - mx), e1 = expf(v.y - mx), e2 = expf(v.z - mx), e3 = expf(v.w - mx);
  float sm = e0 + e1 + e2 + e3;
  #pragma unroll
  for (int off = 32; off > 0; off >>= 1) sm += __shfl_xor(sm, off);
  if ((t & 63) == 0) rs[t >> 6] = sm;
  __syncthreads();
  sm = rs[0] + rs[1] + rs[2] + rs[3];
  const float inv = 1.0f / sm;
  v.x = e0 * inv; v.y = e1 * inv; v.z = e2 * inv; v.w = e3 * inv;
  *(float4*)&row[t * 4] = v;
}

// ---------------------------------------------------------------------------
// One streaming pass over x per (b,h): all 8 pooling scales (half-window
// hierarchy) -> P rows (bf16), plus xa[b,h] = sum_s attn[b,s]*x[b,s,h].
// Level L: chunk stride 4*2^L = stride of scale i=7-L; size = 8<<L.
// ---------------------------------------------------------------------------
__global__ __launch_bounds__(256) void pool_kernel(const float* __restrict__ x,
    const float* __restrict__ attn, uint16_t* __restrict__ P,
    float* __restrict__ xa)
{
  const int b = blockIdx.y;
  const int h = blockIdx.x * 256 + threadIdx.x;
  __shared__ float at[SS];
  #pragma unroll
  for (int j = 0; j < 4; ++j) at[threadIdx.x + j * 256] = attn[(size_t)b * SS + threadIdx.x + j * 256];
  __syncthreads();
  const float* xp = x + (size_t)b * SS * HH + h;
  float lacc[8] = {0,0,0,0,0,0,0,0};
  float lprev[8] = {0,0,0,0,0,0,0,0};
  float xacc = 0.f, chunk = 0.f;
  for (int s8 = 0; s8 < 128; ++s8) {
    float v[8];
    #pragma unroll
    for (int j = 0; j < 8; ++j) v[j] = xp[(size_t)(s8 * 8 + j) * HH];
    #pragma unroll
    for (int j = 0; j < 8; ++j) {
      const int s = s8 * 8 + j;
      xacc += at[s] * v[j];
      chunk += v[j];
      if ((j & 3) == 3) {
        const int cidx = s >> 2;
        const float c = chunk; chunk = 0.f;
        #pragma unroll
        for (int L = 0; L < 8; ++L) {
          lacc[L] += c;
          if (((cidx + 1) & ((1 << L) - 1)) == 0) {
            const int mh = ((cidx + 1) >> L) - 1;   // completed half-window idx
            if (mh >= 1) {
              const int i  = 7 - L;
              const int ni = (256 >> L) - 1;
              const int row = PBrow_c[i] + b * ni + (mh - 1);
              const float inv_size = 1.0f / (float)(8 << L);
              P[(size_t)row * HH + h] = f2bf((lprev[L] + lacc[L]) * inv_size);
            }
            lprev[L] = lacc[L]; lacc[L] = 0.f;
          }
        }
      }
    }
  }
  xa[(size_t)b * HH + h] = xacc;
}

// ---------------------------------------------------------------------------
// feat = tanh(P @ Wp[scale] + bp[scale]), bf16 in / fp32 accum / bf16 out.
// 128x128 tile, 256 thr, 8x8 per thread, Kt=16. grid = (8 n-tiles, 255 row-tiles)
// ---------------------------------------------------------------------------
__global__ __launch_bounds__(256) void feat_gemm(const uint16_t* __restrict__ P,
    const float* __restrict__ Wp, const float* __restrict__ bp,
    uint16_t* __restrict__ feat)
{
  __shared__ float As[16][128];   // [k][m]
  __shared__ float Bs[16][128];   // [k][n]
  const int t = threadIdx.x;
  const int ty = blockIdx.y;
  const int scale = 31 - __clz(ty + 1);          // tiles per scale = 2^i, cum 2^(i+1)-1
  const int tloc  = ty - ((1 << scale) - 1);
  const int row0  = PBrow_c[scale] + tloc * 128;
  const float* Wps = Wp + (size_t)scale * HH * HH;
  const float* bps = bp + scale * HH;
  const int nt = blockIdx.x;
  const int m0 = (t >> 4) << 2;
  const int n0 = (t & 15) << 2;
  const int ar = t >> 1;               // A staging: row 0..127
  const int ak = (t & 1) << 3;         // k half 0/8
  const int bk = t >> 4;               // B staging: k 0..15
  const int bn = (t & 15) << 3;        // n 0..120
  float acc[8][8] = {};
  for (int k0 = 0; k0 < HH; k0 += 16) {
    const uint4 araw = *(const uint4*)(P + (size_t)(row0 + ar) * HH + k0 + ak);
    const float4 b0 = *(const float4*)(Wps + (size_t)(k0 + bk) * HH + nt * 128 + bn);
    const float4 b1 = *(const float4*)(Wps + (size_t)(k0 + bk) * HH + nt * 128 + bn + 4);
    const uint32_t ua[4] = {araw.x, araw.y, araw.z, araw.w};
    #pragma unroll
    for (int j = 0; j < 4; ++j) {
      As[ak + 2 * j + 0][ar] = bf_lo(ua[j]);
      As[ak + 2 * j + 1][ar] = bf_hi(ua[j]);
    }
    *(float4*)&Bs[bk][bn]     = b0;
    *(float4*)&Bs[bk][bn + 4] = b1;
    __syncthreads();
    #pragma unroll
    for (int k = 0; k < 16; ++k) {
      const float4 a0 = *(const float4*)&As[k][m0];
      const float4 a1 = *(const float4*)&As[k][m0 + 64];
      const float4 v0 = *(const float4*)&Bs[k][n0];
      const float4 v1 = *(const float4*)&Bs[k][n0 + 64];
      const float a[8]  = {a0.x, a0.y, a0.z, a0.w, a1.x, a1.y, a1.z, a1.w};
      const float bb[8] = {v0.x, v0.y, v0.z, v0.w, v1.x, v1.y, v1.z, v1.w};
      #pragma unroll
      for (int i2 = 0; i2 < 8; ++i2)
        #pragma unroll
        for (int j2 = 0; j2 < 8; ++j2)
          acc[i2][j2] += a[i2] * bb[j2];
    }
    __syncthreads();
  }
  #pragma unroll
  for (int i2 = 0; i2 < 8; ++i2) {
    const int rr = row0 + m0 + i2 + ((i2 < 4) ? 0 : 60);   // m0+i2 / m0+64+(i2-4)
    #pragma unroll
    for (int jh = 0; jh < 2; ++jh) {
      const int nb2 = nt * 128 + n0 + jh * 64;
      const float f0 = tanhf(acc[i2][jh * 4 + 0] + bps[nb2 + 0]);
      const float f1 = tanhf(acc[i2][jh * 4 + 1] + bps[nb2 + 1]);
      const float f2 = tanhf(acc[i2][jh * 4 + 2] + bps[nb2 + 2]);
      const float f3 = tanhf(acc[i2][jh * 4 + 3] + bps[nb2 + 3]);
      uint2 pk;
      pk.x = (uint32_t)f2bf(f0) | ((uint32_t)f2bf(f1) << 16);
      pk.y = (uint32_t)f2bf(f2) | ((uint32_t)f2bf(f3) << 16);
      *(uint2*)(feat + (size_t)rr * HH + nb2) = pk;
    }
  }
}

// ---------------------------------------------------------------------------
// fa logits: l[prow] = (q[b] . feat[prow]) / 32   (one wave per real row)
// ---------------------------------------------------------------------------
__global__ __launch_bounds__(256) void falogit_kernel(const uint16_t* __restrict__ feat,
    const float* __restrict__ q, float* __restrict__ l)
{
  const int w = threadIdx.x >> 6, lane = threadIdx.x & 63;
  const int r = blockIdx.x * 4 + w;        // real row 0..32127
  int sc = 0;
  #pragma unroll
  for (int i = 1; i < 8; ++i) if (r >= realbase_c[i]) sc = i;
  const int local = r - realbase_c[sc];
  const int ni = (2 << sc) - 1;
  const int b = local / ni;
  const int prow = PBrow_c[sc] + local;
  const uint16_t* fr = feat + (size_t)prow * HH + lane * 16;
  const float*    qr = q + (size_t)b * HH + lane * 16;
  const uint4 f0 = *(const uint4*)fr;
  const uint4 f1 = *(const uint4*)(fr + 8);
  const float4 q0 = *(const float4*)(qr + 0);
  const float4 q1 = *(const float4*)(qr + 4);
  const float4 q2 = *(const float4*)(qr + 8);
  const float4 q3 = *(const float4*)(qr + 12);
  const uint32_t uf[8] = {f0.x, f0.y, f0.z, f0.w, f1.x, f1.y, f1.z, f1.w};
  const float qv[16] = {q0.x,q0.y,q0.z,q0.w, q1.x,q1.y,q1.z,q1.w,
                        q2.x,q2.y,q2.z,q2.w, q3.x,q3.y,q3.z,q3.w};
  float p = 0.f;
  #pragma unroll
  for (int j = 0; j < 8; ++j) {
    p += bf_lo(uf[j]) * qv[2 * j];
    p += bf_hi(uf[j]) * qv[2 * j + 1];
  }
  #pragma unroll
  for (int off = 32; off > 0; off >>= 1) p += __shfl_down(p, off);
  if (lane == 0) l[prow] = p * INV32;
}

// ---------------------------------------------------------------------------
// per (scale,b): fa = softmax(l), ctx = fa@feat, combined += si*ctx (atomic)
// ---------------------------------------------------------------------------
__global__ __launch_bounds__(256) void ctx_kernel(const uint16_t* __restrict__ feat,
    const float* __restrict__ l, const float* __restrict__ si,
    float* __restrict__ comb)
{
  const int i = blockIdx.x, b = blockIdx.y, t = threadIdx.x;
  const int ni = (2 << i) - 1;
  const int base = PBrow_c[i] + b * ni;
  __shared__ float fa[256];
  __shared__ float rbuf[4];
  const float lg = (t < ni) ? l[base + t] : -1e30f;
  float mx = lg;
  #pragma unroll
  for (int off = 32; off > 0; off >>= 1) mx = fmaxf(mx, __shfl_xor(mx, off));
  if ((t & 63) == 0) rbuf[t >> 6] = mx;
  __syncthreads();
  mx = fmaxf(fmaxf(rbuf[0], rbuf[1]), fmaxf(rbuf[2], rbuf[3]));
  const float e = (t < ni) ? expf(lg - mx) : 0.f;
  float sm = e;
  #pragma unroll
  for (int off = 32; off > 0; off >>= 1) sm += __shfl_xor(sm, off);
  __syncthreads();
  if ((t & 63) == 0) rbuf[t >> 6] = sm;
  __syncthreads();
  sm = rbuf[0] + rbuf[1] + rbuf[2] + rbuf[3];
  fa[t] = e / sm;
  __syncthreads();
  float c0 = 0.f, c1 = 0.f, c2 = 0.f, c3 = 0.f;
  const int hb = t * 4;
  for (int n = 0; n < ni; ++n) {
    const float fn = fa[n];
    const uint2 u = *(const uint2*)(feat + (size_t)(base + n) * HH + hb);
    c0 += fn * bf_lo(u.x);
    c1 += fn * bf_hi(u.x);
    c2 += fn * bf_lo(u.y);
    c3 += fn * bf_hi(u.y);
  }
  const float sw = si[b * NSS + i];
  atomicAdd(&comb[(size_t)b * HH + hb + 0], sw * c0);
  atomicAdd(&comb[(size_t)b * HH + hb + 1], sw * c1);
  atomicAdd(&comb[(size_t)b * HH + hb + 2], sw * c2);
  atomicAdd(&comb[(size_t)b * HH + hb + 3], sw * c3);
}

// ---------------------------------------------------------------------------
extern "C" void kernel_launch(void* const* d_in, const int* in_sizes, int n_in,
                              void* d_out, int out_size, void* d_ws, size_t ws_size,
                              hipStream_t stream) {
  (void)in_sizes; (void)n_in; (void)out_size; (void)ws_size;
  const float* x  = (const float*)d_in[0];
  const float* Wq = (const float*)d_in[1];
  const float* bq = (const float*)d_in[2];
  const float* Wk = (const float*)d_in[3];
  // d_in[4] = bk: provably unused (constant shift inside softmax)
  const float* Wv = (const float*)d_in[5];
  const float* bv = (const float*)d_in[6];
  const float* Wp = (const float*)d_in[7];
  const float* bp = (const float*)d_in[8];
  const float* Ws = (const float*)d_in[9];
  const float* bs = (const float*)d_in[10];
  const float* Wo = (const float*)d_in[11];
  const float* bo = (const float*)d_in[12];
  float* out = (float*)d_out;
  char* ws = (char*)d_ws;

  const size_t P_BYTES = (size_t)32640 * HH * 2;   // 66,846,720
  uint16_t* P    = (uint16_t*)ws;
  uint16_t* feat = (uint16_t*)(ws + P_BYTES);
  float* q    = (float*)(ws + 2 * P_BYTES);
  float* qk   = q    + (size_t)BB * HH;
  float* comb = qk   + (size_t)BB * HH;
  float* D    = comb + (size_t)BB * HH;
  float* attn = D    + (size_t)BB * HH;
  float* xa   = attn + (size_t)BB * SS;
  float* si   = xa   + (size_t)BB * HH;
  float* l    = si   + (size_t)BB * NSS;

  // zero atomic-accumulated buffers (q, qk, comb, D are contiguous) + d_out
  hipMemsetAsync(q, 0, (size_t)4 * BB * HH * sizeof(float), stream);
  hipMemsetAsync(d_out, 0, (size_t)BB * HH * sizeof(float), stream);

  // q = x_last @ Wq + bq
  gemm64<false><<<dim3(16, 4), 256, 0, stream>>>(x + (size_t)(SS - 1) * HH, (size_t)SS * HH, Wq, bq, nullptr, q);
  // scale_importance
  si_kernel<<<BB, 256, 0, stream>>>(x, Ws, bs, si);
  // qk = Wk @ q (per batch)  <=>  qk[b][i] = sum_j q[b][j]*Wk[i][j]
  gemm64<true><<<dim3(16, 4), 256, 0, stream>>>(q, (size_t)HH, Wk, nullptr, nullptr, qk);
  // attention logits over x, pass 1
  score_kernel<<<dim3(128, BB), 256, 0, stream>>>(x, qk, attn);
  softmax_s<<<BB, 256, 0, stream>>>(attn);
  // pooling hierarchy + attn-weighted x accumulation, pass 2
  pool_kernel<<<dim3(4, BB), 256, 0, stream>>>(x, attn, P, xa);
  // the big one: feat = tanh(P @ Wp + bp)
  feat_gemm<<<dim3(8, 255), 256, 0, stream>>>(P, Wp, bp, feat);
  // fa logits, softmax+ctx+combine
  falogit_kernel<<<8032, 256, 0, stream>>>(feat, q, l);
  ctx_kernel<<<dim3(NSS, BB), 256, 0, stream>>>(feat, l, si, comb);
  // D = xa @ Wv + bv + combined   (= base_context + combined)
  gemm64<false><<<dim3(16, 4), 256, 0, stream>>>(xa, (size_t)HH, Wv, bv, comb, D);
  // out = D @ Wo + bo
  gemm64<false><<<dim3(16, 4), 256, 0, stream>>>(D, (size_t)HH, Wo, bo, nullptr, out);
}

// Round 2
// 859.582 us; speedup vs baseline: 1.5945x; 1.5945x over previous
//
#include <hip/hip_runtime.h>
#include <cstdint>
#include <cstddef>

// Problem constants (compile-time per reference)
#define BB 64
#define SS 1024
#define HH 1024
#define NSS 8

// scale i: size = 1024>>i, stride = size/2, n_i = 1024/stride - 1 = 2^(i+1)-1
// P rows padded per scale to multiple of 128: region = 64*(n_i+1) = 128*2^i rows
__device__ __constant__ int PBrow_c[8]    = {0,128,384,896,1920,3968,8064,16256};   // padded row base per scale
__device__ __constant__ int realbase_c[8] = {0,64,256,704,1664,3648,7680,15808};    // cumulative real rows
// total padded rows = 32640, total real rows = 32128

#define INV32 0.03125f   // 1/sqrt(H) = 1/sqrt(H*T)

typedef __attribute__((ext_vector_type(8))) short short8;   // 8 bf16 (4 VGPRs)
typedef __attribute__((ext_vector_type(4))) float f32x4;

__device__ __forceinline__ uint16_t f2bf(float f) {
  union { float f; uint32_t u; } v; v.f = f;
  uint32_t r = v.u + 0x7fffu + ((v.u >> 16) & 1u);   // RNE; inputs are finite/bounded
  return (uint16_t)(r >> 16);
}
__device__ __forceinline__ float bf_lo(uint32_t w) { return __uint_as_float(w << 16); }
__device__ __forceinline__ float bf_hi(uint32_t w) { return __uint_as_float(w & 0xffff0000u); }

// async global->LDS, 16 bytes per lane. LDS dest is wave-uniform base + lane*16.
__device__ __forceinline__ void gld_lds16(const void* g, void* l) {
  __builtin_amdgcn_global_load_lds((const __attribute__((address_space(1))) uint32_t*)g,
                                   (__attribute__((address_space(3))) uint32_t*)l, 16, 0, 0);
}

// ---------------------------------------------------------------------------
// Skinny GEMM: out[64][1024] (+)= A[64][1024] @ W (+ bias + addb), split-K=4
// TRANSB=false: W indexed [k][n]; TRANSB=true: W indexed [n][k]
// out MUST be pre-zeroed (atomicAdd accumulation across k-splits).
// ---------------------------------------------------------------------------
template<bool TRANSB>
__global__ __launch_bounds__(256) void gemm64(
    const float* __restrict__ A, size_t a_stride,
    const float* __restrict__ W,
    const float* __restrict__ bias,
    const float* __restrict__ addb,
    float* __restrict__ out)
{
  __shared__ float As[64][68];   // [k][m], pad 68 keeps float4 16B-aligned
  __shared__ float Bs[64][68];   // [k][n]
  const int t  = threadIdx.x;
  const int nt = blockIdx.x;     // 16 n-tiles of 64
  const int ks = blockIdx.y;     // 4 k-splits of 256
  const int m0 = (t >> 4) << 2;
  const int n0 = (t & 15) << 2;
  float acc[4][4] = {};
  for (int kt = 0; kt < 4; ++kt) {
    const int k0 = ks * 256 + kt * 64;
    { // A tile 64x64 -> As[k][m]
      const int m  = t >> 2;
      const int kb = (t & 3) << 4;
      #pragma unroll
      for (int j = 0; j < 4; ++j) {
        const int k = kb + j * 4;
        const float4 v = *(const float4*)(A + (size_t)m * a_stride + k0 + k);
        As[k+0][m] = v.x; As[k+1][m] = v.y; As[k+2][m] = v.z; As[k+3][m] = v.w;
      }
    }
    if (!TRANSB) {
      const int k  = t >> 2;
      const int nb = (t & 3) << 4;
      #pragma unroll
      for (int j = 0; j < 4; ++j) {
        const int n = nb + j * 4;
        *(float4*)&Bs[k][n] = *(const float4*)(W + (size_t)(k0 + k) * HH + nt * 64 + n);
      }
    } else {
      const int n  = t >> 2;
      const int kb = (t & 3) << 4;
      #pragma unroll
      for (int j = 0; j < 4; ++j) {
        const int k = kb + j * 4;
        const float4 v = *(const float4*)(W + (size_t)(nt * 64 + n) * HH + k0 + k);
        Bs[k+0][n] = v.x; Bs[k+1][n] = v.y; Bs[k+2][n] = v.z; Bs[k+3][n] = v.w;
      }
    }
    __syncthreads();
    #pragma unroll 16
    for (int k = 0; k < 64; ++k) {
      const float4 av = *(const float4*)&As[k][m0];
      const float4 bv = *(const float4*)&Bs[k][n0];
      const float a[4] = {av.x, av.y, av.z, av.w};
      const float b[4] = {bv.x, bv.y, bv.z, bv.w};
      #pragma unroll
      for (int i2 = 0; i2 < 4; ++i2)
        #pragma unroll
        for (int j2 = 0; j2 < 4; ++j2)
          acc[i2][j2] += a[i2] * b[j2];
    }
    __syncthreads();
  }
  #pragma unroll
  for (int i2 = 0; i2 < 4; ++i2) {
    const int m = m0 + i2;
    #pragma unroll
    for (int j2 = 0; j2 < 4; ++j2) {
      const int n = nt * 64 + n0 + j2;
      float v = acc[i2][j2];
      if (ks == 0) {
        if (bias) v += bias[n];
        if (addb) v += addb[(size_t)m * HH + n];
      }
      atomicAdd(out + (size_t)m * HH + n, v);
    }
  }
}

// ---------------------------------------------------------------------------
// scale_importance = softmax(x_last @ Ws + bs) per batch  (tiny)
// ---------------------------------------------------------------------------
__global__ __launch_bounds__(256) void si_kernel(const float* __restrict__ x,
    const float* __restrict__ Ws, const float* __restrict__ bs,
    float* __restrict__ si)
{
  const int b = blockIdx.x, t = threadIdx.x;
  const int n = t & 7, kc = t >> 3;            // 32 k-chunks of 32
  const float* xl = x + ((size_t)b * SS + (SS - 1)) * HH;
  float p = 0.f;
  for (int kk = 0; kk < 32; ++kk) {
    const int k = kc * 32 + kk;
    p += xl[k] * Ws[k * NSS + n];
  }
  __shared__ float red[32][9];
  __shared__ float lg[8];
  red[kc][n] = p;
  __syncthreads();
  if (t < 8) {
    float s2 = bs[t];
    for (int c = 0; c < 32; ++c) s2 += red[c][t];
    lg[t] = s2;
  }
  __syncthreads();
  if (t == 0) {
    float mx = lg[0];
    #pragma unroll
    for (int j = 1; j < 8; ++j) mx = fmaxf(mx, lg[j]);
    float e[8]; float sm = 0.f;
    #pragma unroll
    for (int j = 0; j < 8; ++j) { e[j] = expf(lg[j] - mx); sm += e[j]; }
    const float inv = 1.0f / sm;
    #pragma unroll
    for (int j = 0; j < 8; ++j) si[b * NSS + j] = e[j] * inv;
  }
}

// ---------------------------------------------------------------------------
// score logits: attn[b][s] = (x[b,s,:] . qk[b,:]) * 1/32
// (q.bk constant over s -> cancels in softmax, exactly)
// ---------------------------------------------------------------------------
__global__ __launch_bounds__(256) void score_kernel(const float* __restrict__ x,
    const float* __restrict__ qk, float* __restrict__ attn)
{
  const int b = blockIdx.y, sc = blockIdx.x;   // 128 chunks of 8 s
  const int t = threadIdx.x;
  const int lane = t & 63, w = t >> 6;
  __shared__ float qks[HH];
  __shared__ float red[8][4];
  *(float4*)&qks[t * 4] = *(const float4*)&qk[b * HH + t * 4];
  __syncthreads();
  for (int ss = 0; ss < 8; ++ss) {
    const int s = sc * 8 + ss;
    const float4 xv = *(const float4*)&x[((size_t)b * SS + s) * HH + t * 4];
    const float4 qv = *(const float4*)&qks[t * 4];
    float p = xv.x * qv.x + xv.y * qv.y + xv.z * qv.z + xv.w * qv.w;
    #pragma unroll
    for (int off = 32; off > 0; off >>= 1) p += __shfl_down(p, off);
    if (lane == 0) red[ss][w] = p;
  }
  __syncthreads();
  if (t < 8) {
    const float v = (red[t][0] + red[t][1] + red[t][2] + red[t][3]) * INV32;
    attn[(size_t)b * SS + sc * 8 + t] = v;
  }
}

// softmax over S=1024, in place
__global__ __launch_bounds__(256) void softmax_s(float* __restrict__ attn)
{
  const int b = blockIdx.x, t = threadIdx.x;
  float* row = attn + (size_t)b * SS;
  float4 v = *(float4*)&row[t * 4];
  float mx = fmaxf(fmaxf(v.x, v.y), fmaxf(v.z, v.w));
  #pragma unroll
  for (int off = 32; off > 0; off >>= 1) mx = fmaxf(mx, __shfl_xor(mx, off));
  __shared__ float rm[4];
  __shared__ float rs[4];
  if ((t & 63) == 0) rm[t >> 6] = mx;
  __syncthreads();
  mx = fmaxf(fmaxf(rm[0], rm[1]), fmaxf(rm[2], rm[3]));
  const float e0 = expf(v.x - mx), e1 = expf(v.y - mx), e2 = expf(v.z - mx), e3 = expf(v.w - mx);
  float sm = e0 + e1 + e2 + e3;
  #pragma unroll
  for (int off = 32; off > 0; off >>= 1) sm += __shfl_xor(sm, off);
  if ((t & 63) == 0) rs[t >> 6] = sm;
  __syncthreads();
  sm = rs[0] + rs[1] + rs[2] + rs[3];
  const float inv = 1.0f / sm;
  v.x = e0 * inv; v.y = e1 * inv; v.z = e2 * inv; v.w = e3 * inv;
  *(float4*)&row[t * 4] = v;
}

// ---------------------------------------------------------------------------
// One streaming pass over x per (b,h): all 8 pooling scales (half-window
// hierarchy) -> P rows (bf16), plus xa[b,h] = sum_s attn[b,s]*x[b,s,h].
// Level L: chunk stride 4*2^L = stride of scale i=7-L; size = 8<<L.
// ---------------------------------------------------------------------------
__global__ __launch_bounds__(256) void pool_kernel(const float* __restrict__ x,
    const float* __restrict__ attn, uint16_t* __restrict__ P,
    float* __restrict__ xa)
{
  const int b = blockIdx.y;
  const int h = blockIdx.x * 256 + threadIdx.x;
  __shared__ float at[SS];
  #pragma unroll
  for (int j = 0; j < 4; ++j) at[threadIdx.x + j * 256] = attn[(size_t)b * SS + threadIdx.x + j * 256];
  __syncthreads();
  const float* xp = x + (size_t)b * SS * HH + h;
  float lacc[8] = {0,0,0,0,0,0,0,0};
  float lprev[8] = {0,0,0,0,0,0,0,0};
  float xacc = 0.f, chunk = 0.f;
  for (int s8 = 0; s8 < 128; ++s8) {
    float v[8];
    #pragma unroll
    for (int j = 0; j < 8; ++j) v[j] = xp[(size_t)(s8 * 8 + j) * HH];
    #pragma unroll
    for (int j = 0; j < 8; ++j) {
      const int s = s8 * 8 + j;
      xacc += at[s] * v[j];
      chunk += v[j];
      if ((j & 3) == 3) {
        const int cidx = s >> 2;
        const float c = chunk; chunk = 0.f;
        #pragma unroll
        for (int L = 0; L < 8; ++L) {
          lacc[L] += c;
          if (((cidx + 1) & ((1 << L) - 1)) == 0) {
            const int mh = ((cidx + 1) >> L) - 1;   // completed half-window idx
            if (mh >= 1) {
              const int i  = 7 - L;
              const int ni = (256 >> L) - 1;
              const int row = PBrow_c[i] + b * ni + (mh - 1);
              const float inv_size = 1.0f / (float)(8 << L);
              P[(size_t)row * HH + h] = f2bf((lprev[L] + lacc[L]) * inv_size);
            }
            lprev[L] = lacc[L]; lacc[L] = 0.f;
          }
        }
      }
    }
  }
  xa[(size_t)b * HH + h] = xacc;
}

// ---------------------------------------------------------------------------
// Wp fp32 [s][k][n] -> WpT bf16 [s][n][k]  (transpose + downconvert)
// 32x32 tiles, LDS pad 33 breaks bank conflicts on the transposed read.
// ---------------------------------------------------------------------------
__global__ __launch_bounds__(256) void wcvt(const float* __restrict__ Wp,
                                            uint16_t* __restrict__ WpT)
{
  __shared__ float tile[32][33];
  const int s = blockIdx.z;
  const int n0 = blockIdx.x * 32, k0 = blockIdx.y * 32;
  const float* src = Wp + (size_t)s * HH * HH;
  uint16_t* dst = WpT + (size_t)s * HH * HH;
  const int t = threadIdx.x;
  #pragma unroll
  for (int i = 0; i < 4; ++i) {
    const int kl = i * 8 + (t >> 5), nl = t & 31;
    tile[kl][nl] = src[(size_t)(k0 + kl) * HH + n0 + nl];
  }
  __syncthreads();
  #pragma unroll
  for (int i = 0; i < 4; ++i) {
    const int nl = i * 8 + (t >> 5), kl = t & 31;
    dst[(size_t)(n0 + nl) * HH + k0 + kl] = f2bf(tile[kl][nl]);
  }
}

// ---------------------------------------------------------------------------
// feat = tanh(P @ Wp[scale]^T + bp[scale])  via MFMA bf16.
// A = P bf16 [row][k], B = WpT bf16 [n][k] (both row-major along k).
// 128x128 tile, BK=32, 256 thr = 4 waves in 2x2 of 64x64.
// LDS layout per tile: 16B blocks indexed [khalf(0..3)][row(0..127)] so that
// global_load_lds staging is lane-contiguous AND ds_read_b128 fragment reads
// are conflict-free (each quad reads 256B contiguous).
// mfma_f32_16x16x32_bf16: A[m=lane&15][k=quad*8+j]; C/D col=lane&15,
// row=quad*4+reg (guide-verified layouts).
// ---------------------------------------------------------------------------
__global__ __launch_bounds__(256) void feat_gemm(const uint16_t* __restrict__ P,
    const uint16_t* __restrict__ WpT, const float* __restrict__ bp,
    uint16_t* __restrict__ feat)
{
  __shared__ __align__(16) uint16_t As[4 * 128 * 8];   // 8 KB
  __shared__ __align__(16) uint16_t Bs[4 * 128 * 8];   // 8 KB
  const int t = threadIdx.x;
  const int w = t >> 6, lane = t & 63;
  const int quad = lane >> 4, l16 = lane & 15;
  const int ty = blockIdx.y;
  const int scale = 31 - __clz(ty + 1);          // tiles per scale = 2^i
  const int tloc  = ty - ((1 << scale) - 1);
  const int row0  = PBrow_c[scale] + tloc * 128;
  const uint16_t* Wps = WpT + (size_t)scale * HH * HH;
  const float* bps = bp + scale * HH;
  const int ncol0 = blockIdx.x * 128;
  const int wm = (w & 1) * 64, wn = (w >> 1) * 64;

  f32x4 acc[4][4];
  #pragma unroll
  for (int mt = 0; mt < 4; ++mt)
    #pragma unroll
    for (int nt = 0; nt < 4; ++nt)
      acc[mt][nt] = (f32x4){0.f, 0.f, 0.f, 0.f};

  for (int k0 = 0; k0 < HH; k0 += 32) {
    // stage A and B tiles: 8 x 1KB wave-instructions each, 2 per wave per tile
    #pragma unroll
    for (int i = w; i < 8; i += 4) {
      const int khalf = i >> 1, r0 = (i & 1) * 64;
      gld_lds16(P + (size_t)(row0 + r0 + lane) * HH + k0 + khalf * 8,
                As + (size_t)i * 512);
      gld_lds16(Wps + (size_t)(ncol0 + r0 + lane) * HH + k0 + khalf * 8,
                Bs + (size_t)i * 512);
    }
    __syncthreads();   // compiler drains vmcnt before barrier
    short8 af[4], bf[4];
    const short8* Asv = (const short8*)As;
    const short8* Bsv = (const short8*)Bs;
    #pragma unroll
    for (int mt = 0; mt < 4; ++mt) af[mt] = Asv[quad * 128 + wm + mt * 16 + l16];
    #pragma unroll
    for (int nt = 0; nt < 4; ++nt) bf[nt] = Bsv[quad * 128 + wn + nt * 16 + l16];
    #pragma unroll
    for (int mt = 0; mt < 4; ++mt)
      #pragma unroll
      for (int nt = 0; nt < 4; ++nt)
        acc[mt][nt] = __builtin_amdgcn_mfma_f32_16x16x32_bf16(af[mt], bf[nt], acc[mt][nt], 0, 0, 0);
    __syncthreads();
  }

  // epilogue: bias + tanh + bf16 store
  #pragma unroll
  for (int nt = 0; nt < 4; ++nt) {
    const int col = ncol0 + wn + nt * 16 + l16;
    const float bpv = bps[col];
    #pragma unroll
    for (int mt = 0; mt < 4; ++mt) {
      #pragma unroll
      for (int r = 0; r < 4; ++r) {
        const int row = row0 + wm + mt * 16 + quad * 4 + r;
        feat[(size_t)row * HH + col] = f2bf(tanhf(acc[mt][nt][r] + bpv));
      }
    }
  }
}

// ---------------------------------------------------------------------------
// fa logits: l[prow] = (q[b] . feat[prow]) / 32   (one wave per real row)
// ---------------------------------------------------------------------------
__global__ __launch_bounds__(256) void falogit_kernel(const uint16_t* __restrict__ feat,
    const float* __restrict__ q, float* __restrict__ l)
{
  const int w = threadIdx.x >> 6, lane = threadIdx.x & 63;
  const int r = blockIdx.x * 4 + w;        // real row 0..32127
  int sc = 0;
  #pragma unroll
  for (int i = 1; i < 8; ++i) if (r >= realbase_c[i]) sc = i;
  const int local = r - realbase_c[sc];
  const int ni = (2 << sc) - 1;
  const int b = local / ni;
  const int prow = PBrow_c[sc] + local;
  const uint16_t* fr = feat + (size_t)prow * HH + lane * 16;
  const float*    qr = q + (size_t)b * HH + lane * 16;
  const uint4 f0 = *(const uint4*)fr;
  const uint4 f1 = *(const uint4*)(fr + 8);
  const float4 q0 = *(const float4*)(qr + 0);
  const float4 q1 = *(const float4*)(qr + 4);
  const float4 q2 = *(const float4*)(qr + 8);
  const float4 q3 = *(const float4*)(qr + 12);
  const uint32_t uf[8] = {f0.x, f0.y, f0.z, f0.w, f1.x, f1.y, f1.z, f1.w};
  const float qv[16] = {q0.x,q0.y,q0.z,q0.w, q1.x,q1.y,q1.z,q1.w,
                        q2.x,q2.y,q2.z,q2.w, q3.x,q3.y,q3.z,q3.w};
  float p = 0.f;
  #pragma unroll
  for (int j = 0; j < 8; ++j) {
    p += bf_lo(uf[j]) * qv[2 * j];
    p += bf_hi(uf[j]) * qv[2 * j + 1];
  }
  #pragma unroll
  for (int off = 32; off > 0; off >>= 1) p += __shfl_down(p, off);
  if (lane == 0) l[prow] = p * INV32;
}

// ---------------------------------------------------------------------------
// per (scale,b): fa = softmax(l), ctx = fa@feat, combined += si*ctx (atomic)
// ---------------------------------------------------------------------------
__global__ __launch_bounds__(256) void ctx_kernel(const uint16_t* __restrict__ feat,
    const float* __restrict__ l, const float* __restrict__ si,
    float* __restrict__ comb)
{
  const int i = blockIdx.x, b = blockIdx.y, t = threadIdx.x;
  const int ni = (2 << i) - 1;
  const int base = PBrow_c[i] + b * ni;
  __shared__ float fa[256];
  __shared__ float rbuf[4];
  const float lg = (t < ni) ? l[base + t] : -1e30f;
  float mx = lg;
  #pragma unroll
  for (int off = 32; off > 0; off >>= 1) mx = fmaxf(mx, __shfl_xor(mx, off));
  if ((t & 63) == 0) rbuf[t >> 6] = mx;
  __syncthreads();
  mx = fmaxf(fmaxf(rbuf[0], rbuf[1]), fmaxf(rbuf[2], rbuf[3]));
  const float e = (t < ni) ? expf(lg - mx) : 0.f;
  float sm = e;
  #pragma unroll
  for (int off = 32; off > 0; off >>= 1) sm += __shfl_xor(sm, off);
  __syncthreads();
  if ((t & 63) == 0) rbuf[t >> 6] = sm;
  __syncthreads();
  sm = rbuf[0] + rbuf[1] + rbuf[2] + rbuf[3];
  fa[t] = e / sm;
  __syncthreads();
  float c0 = 0.f, c1 = 0.f, c2 = 0.f, c3 = 0.f;
  const int hb = t * 4;
  for (int n = 0; n < ni; ++n) {
    const float fn = fa[n];
    const uint2 u = *(const uint2*)(feat + (size_t)(base + n) * HH + hb);
    c0 += fn * bf_lo(u.x);
    c1 += fn * bf_hi(u.x);
    c2 += fn * bf_lo(u.y);
    c3 += fn * bf_hi(u.y);
  }
  const float sw = si[b * NSS + i];
  atomicAdd(&comb[(size_t)b * HH + hb + 0], sw * c0);
  atomicAdd(&comb[(size_t)b * HH + hb + 1], sw * c1);
  atomicAdd(&comb[(size_t)b * HH + hb + 2], sw * c2);
  atomicAdd(&comb[(size_t)b * HH + hb + 3], sw * c3);
}

// ---------------------------------------------------------------------------
extern "C" void kernel_launch(void* const* d_in, const int* in_sizes, int n_in,
                              void* d_out, int out_size, void* d_ws, size_t ws_size,
                              hipStream_t stream) {
  (void)in_sizes; (void)n_in; (void)out_size; (void)ws_size;
  const float* x  = (const float*)d_in[0];
  const float* Wq = (const float*)d_in[1];
  const float* bq = (const float*)d_in[2];
  const float* Wk = (const float*)d_in[3];
  // d_in[4] = bk: provably unused (constant shift inside softmax)
  const float* Wv = (const float*)d_in[5];
  const float* bv = (const float*)d_in[6];
  const float* Wp = (const float*)d_in[7];
  const float* bp = (const float*)d_in[8];
  const float* Ws = (const float*)d_in[9];
  const float* bs = (const float*)d_in[10];
  const float* Wo = (const float*)d_in[11];
  const float* bo = (const float*)d_in[12];
  float* out = (float*)d_out;
  char* ws = (char*)d_ws;

  const size_t P_BYTES   = (size_t)32640 * HH * 2;   // 66,846,720
  const size_t WPT_BYTES = (size_t)NSS * HH * HH * 2; // 16,777,216
  uint16_t* P    = (uint16_t*)ws;
  uint16_t* feat = (uint16_t*)(ws + P_BYTES);
  uint16_t* WpT  = (uint16_t*)(ws + 2 * P_BYTES);
  float* q    = (float*)(ws + 2 * P_BYTES + WPT_BYTES);
  float* qk   = q    + (size_t)BB * HH;
  float* comb = qk   + (size_t)BB * HH;
  float* D    = comb + (size_t)BB * HH;
  float* attn = D    + (size_t)BB * HH;
  float* xa   = attn + (size_t)BB * SS;
  float* si   = xa   + (size_t)BB * HH;
  float* l    = si   + (size_t)BB * NSS;

  // zero atomic-accumulated buffers (q, qk, comb, D are contiguous) + d_out
  hipMemsetAsync(q, 0, (size_t)4 * BB * HH * sizeof(float), stream);
  hipMemsetAsync(d_out, 0, (size_t)BB * HH * sizeof(float), stream);

  // Wp -> bf16 transposed [scale][n][k] for MFMA B-operand
  wcvt<<<dim3(32, 32, NSS), 256, 0, stream>>>(Wp, WpT);
  // q = x_last @ Wq + bq
  gemm64<false><<<dim3(16, 4), 256, 0, stream>>>(x + (size_t)(SS - 1) * HH, (size_t)SS * HH, Wq, bq, nullptr, q);
  // scale_importance
  si_kernel<<<BB, 256, 0, stream>>>(x, Ws, bs, si);
  // qk = Wk @ q (per batch)  <=>  qk[b][i] = sum_j q[b][j]*Wk[i][j]
  gemm64<true><<<dim3(16, 4), 256, 0, stream>>>(q, (size_t)HH, Wk, nullptr, nullptr, qk);
  // attention logits over x, pass 1
  score_kernel<<<dim3(128, BB), 256, 0, stream>>>(x, qk, attn);
  softmax_s<<<BB, 256, 0, stream>>>(attn);
  // pooling hierarchy + attn-weighted x accumulation, pass 2
  pool_kernel<<<dim3(4, BB), 256, 0, stream>>>(x, attn, P, xa);
  // the big one: feat = tanh(P @ WpT^T + bp) via bf16 MFMA
  feat_gemm<<<dim3(8, 255), 256, 0, stream>>>(P, WpT, bp, feat);
  // fa logits, softmax+ctx+combine
  falogit_kernel<<<8032, 256, 0, stream>>>(feat, q, l);
  ctx_kernel<<<dim3(NSS, BB), 256, 0, stream>>>(feat, l, si, comb);
  // D = xa @ Wv + bv + combined   (= base_context + combined)
  gemm64<false><<<dim3(16, 4), 256, 0, stream>>>(xa, (size_t)HH, Wv, bv, comb, D);
  // out = D @ Wo + bo
  gemm64<false><<<dim3(16, 4), 256, 0, stream>>>(D, (size_t)HH, Wo, bo, nullptr, out);
}

// Round 3
// 786.564 us; speedup vs baseline: 1.7426x; 1.0928x over previous
//
#include <hip/hip_runtime.h>
#include <cstdint>
#include <cstddef>

// Problem constants (compile-time per reference)
#define BB 64
#define SS 1024
#define HH 1024
#define NSS 8

// scale i: size = 1024>>i, stride = size/2, n_i = 1024/stride - 1 = 2^(i+1)-1
// P rows padded per scale to multiple of 128: region = 64*(n_i+1) = 128*2^i rows
__device__ __constant__ int PBrow_c[8]    = {0,128,384,896,1920,3968,8064,16256};   // padded row base per scale
__device__ __constant__ int realbase_c[8] = {0,64,256,704,1664,3648,7680,15808};    // cumulative real rows
// total padded rows = 32640 (=255*128), total real rows = 32128

#define INV32 0.03125f   // 1/sqrt(H) = 1/sqrt(H*T)

typedef __attribute__((ext_vector_type(8))) short short8;   // 8 bf16 (4 VGPRs)
typedef __attribute__((ext_vector_type(4))) float f32x4;

__device__ __forceinline__ uint16_t f2bf(float f) {
  union { float f; uint32_t u; } v; v.f = f;
  uint32_t r = v.u + 0x7fffu + ((v.u >> 16) & 1u);   // RNE; inputs are finite/bounded
  return (uint16_t)(r >> 16);
}
__device__ __forceinline__ float bf_lo(uint32_t w) { return __uint_as_float(w << 16); }
__device__ __forceinline__ float bf_hi(uint32_t w) { return __uint_as_float(w & 0xffff0000u); }

// async global->LDS, 16 bytes per lane. LDS dest is wave-uniform base + lane*16.
__device__ __forceinline__ void gld_lds16(const void* g, void* l) {
  __builtin_amdgcn_global_load_lds((const __attribute__((address_space(1))) uint32_t*)g,
                                   (__attribute__((address_space(3))) uint32_t*)l, 16, 0, 0);
}

// Packed tile layout for MFMA operands (the exact LDS staging image):
// elem (row, k) of a 128-row tile group lives at
//   [tile=row>>7][kb2=k>>6][kq=(k>>3)&7][rl=row&127][j=k&7]
// so each (tile,kb2) is a contiguous 16KB block and every 1KB chunk is
// lane-contiguous for global_load_lds.
__device__ __forceinline__ size_t pk_idx(int row, int k) {
  return (((size_t)(row >> 7) * 16 + (k >> 6)) * 8 + ((k >> 3) & 7)) * 1024
         + (size_t)(row & 127) * 8 + (k & 7);
}

// ---------------------------------------------------------------------------
// Skinny GEMM: out[64][1024] (+)= A[64][1024] @ W (+ bias + addb), split-K=4
// TRANSB=false: W indexed [k][n]; TRANSB=true: W indexed [n][k]
// out MUST be pre-zeroed (atomicAdd accumulation across k-splits).
// ---------------------------------------------------------------------------
template<bool TRANSB>
__global__ __launch_bounds__(256) void gemm64(
    const float* __restrict__ A, size_t a_stride,
    const float* __restrict__ W,
    const float* __restrict__ bias,
    const float* __restrict__ addb,
    float* __restrict__ out)
{
  __shared__ float As[64][68];   // [k][m], pad 68 keeps float4 16B-aligned
  __shared__ float Bs[64][68];   // [k][n]
  const int t  = threadIdx.x;
  const int nt = blockIdx.x;     // 16 n-tiles of 64
  const int ks = blockIdx.y;     // 4 k-splits of 256
  const int m0 = (t >> 4) << 2;
  const int n0 = (t & 15) << 2;
  float acc[4][4] = {};
  for (int kt = 0; kt < 4; ++kt) {
    const int k0 = ks * 256 + kt * 64;
    { // A tile 64x64 -> As[k][m]
      const int m  = t >> 2;
      const int kb = (t & 3) << 4;
      #pragma unroll
      for (int j = 0; j < 4; ++j) {
        const int k = kb + j * 4;
        const float4 v = *(const float4*)(A + (size_t)m * a_stride + k0 + k);
        As[k+0][m] = v.x; As[k+1][m] = v.y; As[k+2][m] = v.z; As[k+3][m] = v.w;
      }
    }
    if (!TRANSB) {
      const int k  = t >> 2;
      const int nb = (t & 3) << 4;
      #pragma unroll
      for (int j = 0; j < 4; ++j) {
        const int n = nb + j * 4;
        *(float4*)&Bs[k][n] = *(const float4*)(W + (size_t)(k0 + k) * HH + nt * 64 + n);
      }
    } else {
      const int n  = t >> 2;
      const int kb = (t & 3) << 4;
      #pragma unroll
      for (int j = 0; j < 4; ++j) {
        const int k = kb + j * 4;
        const float4 v = *(const float4*)(W + (size_t)(nt * 64 + n) * HH + k0 + k);
        Bs[k+0][n] = v.x; Bs[k+1][n] = v.y; Bs[k+2][n] = v.z; Bs[k+3][n] = v.w;
      }
    }
    __syncthreads();
    #pragma unroll 16
    for (int k = 0; k < 64; ++k) {
      const float4 av = *(const float4*)&As[k][m0];
      const float4 bv = *(const float4*)&Bs[k][n0];
      const float a[4] = {av.x, av.y, av.z, av.w};
      const float b[4] = {bv.x, bv.y, bv.z, bv.w};
      #pragma unroll
      for (int i2 = 0; i2 < 4; ++i2)
        #pragma unroll
        for (int j2 = 0; j2 < 4; ++j2)
          acc[i2][j2] += a[i2] * b[j2];
    }
    __syncthreads();
  }
  #pragma unroll
  for (int i2 = 0; i2 < 4; ++i2) {
    const int m = m0 + i2;
    #pragma unroll
    for (int j2 = 0; j2 < 4; ++j2) {
      const int n = nt * 64 + n0 + j2;
      float v = acc[i2][j2];
      if (ks == 0) {
        if (bias) v += bias[n];
        if (addb) v += addb[(size_t)m * HH + n];
      }
      atomicAdd(out + (size_t)m * HH + n, v);
    }
  }
}

// ---------------------------------------------------------------------------
// scale_importance = softmax(x_last @ Ws + bs) per batch  (tiny)
// ---------------------------------------------------------------------------
__global__ __launch_bounds__(256) void si_kernel(const float* __restrict__ x,
    const float* __restrict__ Ws, const float* __restrict__ bs,
    float* __restrict__ si)
{
  const int b = blockIdx.x, t = threadIdx.x;
  const int n = t & 7, kc = t >> 3;            // 32 k-chunks of 32
  const float* xl = x + ((size_t)b * SS + (SS - 1)) * HH;
  float p = 0.f;
  for (int kk = 0; kk < 32; ++kk) {
    const int k = kc * 32 + kk;
    p += xl[k] * Ws[k * NSS + n];
  }
  __shared__ float red[32][9];
  __shared__ float lg[8];
  red[kc][n] = p;
  __syncthreads();
  if (t < 8) {
    float s2 = bs[t];
    for (int c = 0; c < 32; ++c) s2 += red[c][t];
    lg[t] = s2;
  }
  __syncthreads();
  if (t == 0) {
    float mx = lg[0];
    #pragma unroll
    for (int j = 1; j < 8; ++j) mx = fmaxf(mx, lg[j]);
    float e[8]; float sm = 0.f;
    #pragma unroll
    for (int j = 0; j < 8; ++j) { e[j] = expf(lg[j] - mx); sm += e[j]; }
    const float inv = 1.0f / sm;
    #pragma unroll
    for (int j = 0; j < 8; ++j) si[b * NSS + j] = e[j] * inv;
  }
}

// ---------------------------------------------------------------------------
// score logits: attn[b][s] = (x[b,s,:] . qk[b,:]) * 1/32
// (q.bk constant over s -> cancels in softmax, exactly)
// ---------------------------------------------------------------------------
__global__ __launch_bounds__(256) void score_kernel(const float* __restrict__ x,
    const float* __restrict__ qk, float* __restrict__ attn)
{
  const int b = blockIdx.y, sc = blockIdx.x;   // 128 chunks of 8 s
  const int t = threadIdx.x;
  const int lane = t & 63, w = t >> 6;
  __shared__ float qks[HH];
  __shared__ float red[8][4];
  *(float4*)&qks[t * 4] = *(const float4*)&qk[b * HH + t * 4];
  __syncthreads();
  for (int ss = 0; ss < 8; ++ss) {
    const int s = sc * 8 + ss;
    const float4 xv = *(const float4*)&x[((size_t)b * SS + s) * HH + t * 4];
    const float4 qv = *(const float4*)&qks[t * 4];
    float p = xv.x * qv.x + xv.y * qv.y + xv.z * qv.z + xv.w * qv.w;
    #pragma unroll
    for (int off = 32; off > 0; off >>= 1) p += __shfl_down(p, off);
    if (lane == 0) red[ss][w] = p;
  }
  __syncthreads();
  if (t < 8) {
    const float v = (red[t][0] + red[t][1] + red[t][2] + red[t][3]) * INV32;
    attn[(size_t)b * SS + sc * 8 + t] = v;
  }
}

// softmax over S=1024, in place
__global__ __launch_bounds__(256) void softmax_s(float* __restrict__ attn)
{
  const int b = blockIdx.x, t = threadIdx.x;
  float* row = attn + (size_t)b * SS;
  float4 v = *(float4*)&row[t * 4];
  float mx = fmaxf(fmaxf(v.x, v.y), fmaxf(v.z, v.w));
  #pragma unroll
  for (int off = 32; off > 0; off >>= 1) mx = fmaxf(mx, __shfl_xor(mx, off));
  __shared__ float rm[4];
  __shared__ float rs[4];
  if ((t & 63) == 0) rm[t >> 6] = mx;
  __syncthreads();
  mx = fmaxf(fmaxf(rm[0], rm[1]), fmaxf(rm[2], rm[3]));
  const float e0 = expf(v.x - mx), e1 = expf(v.y - mx), e2 = expf(v.z - mx), e3 = expf(v.w - mx);
  float sm = e0 + e1 + e2 + e3;
  #pragma unroll
  for (int off = 32; off > 0; off >>= 1) sm += __shfl_xor(sm, off);
  if ((t & 63) == 0) rs[t >> 6] = sm;
  __syncthreads();
  sm = rs[0] + rs[1] + rs[2] + rs[3];
  const float inv = 1.0f / sm;
  v.x = e0 * inv; v.y = e1 * inv; v.z = e2 * inv; v.w = e3 * inv;
  *(float4*)&row[t * 4] = v;
}

// ---------------------------------------------------------------------------
// One streaming pass over x per (b,h): all 8 pooling scales (half-window
// hierarchy) -> P rows (bf16, PACKED tile layout), plus xa[b,h].
// Level L: chunk stride 4*2^L = stride of scale i=7-L; size = 8<<L.
// s unrolled by 16 for more outstanding loads (4 waves/CU only).
// ---------------------------------------------------------------------------
__global__ __launch_bounds__(256) void pool_kernel(const float* __restrict__ x,
    const float* __restrict__ attn, uint16_t* __restrict__ P,
    float* __restrict__ xa)
{
  const int b = blockIdx.y;
  const int h = blockIdx.x * 256 + threadIdx.x;
  __shared__ float at[SS];
  #pragma unroll
  for (int j = 0; j < 4; ++j) at[threadIdx.x + j * 256] = attn[(size_t)b * SS + threadIdx.x + j * 256];
  __syncthreads();
  const float* xp = x + (size_t)b * SS * HH + h;
  float lacc[8] = {0,0,0,0,0,0,0,0};
  float lprev[8] = {0,0,0,0,0,0,0,0};
  float xacc = 0.f, chunk = 0.f;
  for (int s16 = 0; s16 < 64; ++s16) {
    float v[16];
    #pragma unroll
    for (int j = 0; j < 16; ++j) v[j] = xp[(size_t)(s16 * 16 + j) * HH];
    #pragma unroll
    for (int j = 0; j < 16; ++j) {
      const int s = s16 * 16 + j;
      xacc += at[s] * v[j];
      chunk += v[j];
      if ((j & 3) == 3) {
        const int cidx = s >> 2;
        const float c = chunk; chunk = 0.f;
        #pragma unroll
        for (int L = 0; L < 8; ++L) {
          lacc[L] += c;
          if (((cidx + 1) & ((1 << L) - 1)) == 0) {
            const int mh = ((cidx + 1) >> L) - 1;   // completed half-window idx
            if (mh >= 1) {
              const int i  = 7 - L;
              const int ni = (256 >> L) - 1;
              const int row = PBrow_c[i] + b * ni + (mh - 1);
              const float inv_size = 1.0f / (float)(8 << L);
              P[pk_idx(row, h)] = f2bf((lprev[L] + lacc[L]) * inv_size);
            }
            lprev[L] = lacc[L]; lacc[L] = 0.f;
          }
        }
      }
    }
  }
  xa[(size_t)b * HH + h] = xacc;
}

// ---------------------------------------------------------------------------
// Wp fp32 [s][k][n] -> Wpk bf16 packed: per scale, col-tiles of 128, packed
// tile layout over (col, k). 32x32 LDS transpose tiles.
// ---------------------------------------------------------------------------
__global__ __launch_bounds__(256) void wcvt(const float* __restrict__ Wp,
                                            uint16_t* __restrict__ Wpk)
{
  __shared__ float tile[32][33];
  const int s = blockIdx.z;
  const int n0 = blockIdx.x * 32, k0 = blockIdx.y * 32;
  const float* src = Wp + (size_t)s * HH * HH;
  uint16_t* dst = Wpk + (size_t)s * HH * HH;   // scale-region base; pk_idx over (col-row, k)
  const int t = threadIdx.x;
  #pragma unroll
  for (int i = 0; i < 4; ++i) {
    const int kl = i * 8 + (t >> 5), nl = t & 31;
    tile[kl][nl] = src[(size_t)(k0 + kl) * HH + n0 + nl];
  }
  __syncthreads();
  #pragma unroll
  for (int i = 0; i < 4; ++i) {
    const int nl = i * 8 + (t >> 5), kl = t & 31;
    dst[pk_idx(n0 + nl, k0 + kl)] = f2bf(tile[kl][nl]);
  }
}

// ---------------------------------------------------------------------------
// feat = tanh(P @ Wp[scale]^T + bp[scale])  via MFMA bf16.
// Both operands pre-packed: every global_load_lds is a contiguous 1KB burst.
// 128x128 tile, BK=64, 256 thr = 4 waves in 2x2 of 64x64.
// mfma_f32_16x16x32_bf16: A[m=lane&15][k=quad*8+j]; C/D col=lane&15,
// row=quad*4+reg (layouts verified by round-2 pass).
// ---------------------------------------------------------------------------
__global__ __launch_bounds__(256) void feat_gemm(const uint16_t* __restrict__ P,
    const uint16_t* __restrict__ Wpk, const float* __restrict__ bp,
    uint16_t* __restrict__ feat)
{
  __shared__ __align__(16) uint16_t As[8 * 128 * 8];   // 16 KB
  __shared__ __align__(16) uint16_t Bs[8 * 128 * 8];   // 16 KB
  const int t = threadIdx.x;
  const int w = t >> 6, lane = t & 63;
  const int quad = lane >> 4, l16 = lane & 15;
  const int ty = blockIdx.y;
  const int scale = 31 - __clz(ty + 1);          // tiles per scale = 2^i
  const int tloc  = ty - ((1 << scale) - 1);
  const int row0  = PBrow_c[scale] + tloc * 128;
  const int rt    = row0 >> 7;                   // A row-tile index
  const int ct    = blockIdx.x;                  // B col-tile index
  const float* bps = bp + scale * HH;
  const int ncol0 = ct * 128;
  const int wm = (w & 1) * 64, wn = (w >> 1) * 64;

  f32x4 acc[4][4];
  #pragma unroll
  for (int mt = 0; mt < 4; ++mt)
    #pragma unroll
    for (int nt = 0; nt < 4; ++nt)
      acc[mt][nt] = (f32x4){0.f, 0.f, 0.f, 0.f};

  const short8* Asv = (const short8*)As;
  const short8* Bsv = (const short8*)Bs;

  for (int kb2 = 0; kb2 < 16; ++kb2) {
    const uint16_t* Ag = P   + ((size_t)(rt * 16 + kb2)) * 8192;
    const uint16_t* Bg = Wpk + ((size_t)((scale * 8 + ct) * 16 + kb2)) * 8192;
    // 16 x 1KB contiguous bursts per operand, 4 per wave
    #pragma unroll
    for (int i = w; i < 16; i += 4) {
      gld_lds16(Ag + i * 512 + lane * 8, As + i * 512);
      gld_lds16(Bg + i * 512 + lane * 8, Bs + i * 512);
    }
    __syncthreads();
    #pragma unroll
    for (int ks2 = 0; ks2 < 2; ++ks2) {
      short8 af[4], bf[4];
      #pragma unroll
      for (int mt = 0; mt < 4; ++mt) af[mt] = Asv[(ks2 * 4 + quad) * 128 + wm + mt * 16 + l16];
      #pragma unroll
      for (int nt = 0; nt < 4; ++nt) bf[nt] = Bsv[(ks2 * 4 + quad) * 128 + wn + nt * 16 + l16];
      #pragma unroll
      for (int mt = 0; mt < 4; ++mt)
        #pragma unroll
        for (int nt = 0; nt < 4; ++nt)
          acc[mt][nt] = __builtin_amdgcn_mfma_f32_16x16x32_bf16(af[mt], bf[nt], acc[mt][nt], 0, 0, 0);
    }
    __syncthreads();
  }

  // epilogue: bias + tanh + bf16 store (feat stays row-major)
  #pragma unroll
  for (int nt = 0; nt < 4; ++nt) {
    const int col = ncol0 + wn + nt * 16 + l16;
    const float bpv = bps[col];
    #pragma unroll
    for (int mt = 0; mt < 4; ++mt) {
      #pragma unroll
      for (int r = 0; r < 4; ++r) {
        const int row = row0 + wm + mt * 16 + quad * 4 + r;
        feat[(size_t)row * HH + col] = f2bf(tanhf(acc[mt][nt][r] + bpv));
      }
    }
  }
}

// ---------------------------------------------------------------------------
// fa logits: l[prow] = (q[b] . feat[prow]) / 32   (one wave per real row)
// ---------------------------------------------------------------------------
__global__ __launch_bounds__(256) void falogit_kernel(const uint16_t* __restrict__ feat,
    const float* __restrict__ q, float* __restrict__ l)
{
  const int w = threadIdx.x >> 6, lane = threadIdx.x & 63;
  const int r = blockIdx.x * 4 + w;        // real row 0..32127
  int sc = 0;
  #pragma unroll
  for (int i = 1; i < 8; ++i) if (r >= realbase_c[i]) sc = i;
  const int local = r - realbase_c[sc];
  const int ni = (2 << sc) - 1;
  const int b = local / ni;
  const int prow = PBrow_c[sc] + local;
  const uint16_t* fr = feat + (size_t)prow * HH + lane * 16;
  const float*    qr = q + (size_t)b * HH + lane * 16;
  const uint4 f0 = *(const uint4*)fr;
  const uint4 f1 = *(const uint4*)(fr + 8);
  const float4 q0 = *(const float4*)(qr + 0);
  const float4 q1 = *(const float4*)(qr + 4);
  const float4 q2 = *(const float4*)(qr + 8);
  const float4 q3 = *(const float4*)(qr + 12);
  const uint32_t uf[8] = {f0.x, f0.y, f0.z, f0.w, f1.x, f1.y, f1.z, f1.w};
  const float qv[16] = {q0.x,q0.y,q0.z,q0.w, q1.x,q1.y,q1.z,q1.w,
                        q2.x,q2.y,q2.z,q2.w, q3.x,q3.y,q3.z,q3.w};
  float p = 0.f;
  #pragma unroll
  for (int j = 0; j < 8; ++j) {
    p += bf_lo(uf[j]) * qv[2 * j];
    p += bf_hi(uf[j]) * qv[2 * j + 1];
  }
  #pragma unroll
  for (int off = 32; off > 0; off >>= 1) p += __shfl_down(p, off);
  if (lane == 0) l[prow] = p * INV32;
}

// ---------------------------------------------------------------------------
// per (scale,b): fa = softmax(l), ctx = fa@feat, combined += si*ctx (atomic)
// ---------------------------------------------------------------------------
__global__ __launch_bounds__(256) void ctx_kernel(const uint16_t* __restrict__ feat,
    const float* __restrict__ l, const float* __restrict__ si,
    float* __restrict__ comb)
{
  const int i = blockIdx.x, b = blockIdx.y, t = threadIdx.x;
  const int ni = (2 << i) - 1;
  const int base = PBrow_c[i] + b * ni;
  __shared__ float fa[256];
  __shared__ float rbuf[4];
  const float lg = (t < ni) ? l[base + t] : -1e30f;
  float mx = lg;
  #pragma unroll
  for (int off = 32; off > 0; off >>= 1) mx = fmaxf(mx, __shfl_xor(mx, off));
  if ((t & 63) == 0) rbuf[t >> 6] = mx;
  __syncthreads();
  mx = fmaxf(fmaxf(rbuf[0], rbuf[1]), fmaxf(rbuf[2], rbuf[3]));
  const float e = (t < ni) ? expf(lg - mx) : 0.f;
  float sm = e;
  #pragma unroll
  for (int off = 32; off > 0; off >>= 1) sm += __shfl_xor(sm, off);
  __syncthreads();
  if ((t & 63) == 0) rbuf[t >> 6] = sm;
  __syncthreads();
  sm = rbuf[0] + rbuf[1] + rbuf[2] + rbuf[3];
  fa[t] = e / sm;
  __syncthreads();
  float c0 = 0.f, c1 = 0.f, c2 = 0.f, c3 = 0.f;
  const int hb = t * 4;
  for (int n = 0; n < ni; ++n) {
    const float fn = fa[n];
    const uint2 u = *(const uint2*)(feat + (size_t)(base + n) * HH + hb);
    c0 += fn * bf_lo(u.x);
    c1 += fn * bf_hi(u.x);
    c2 += fn * bf_lo(u.y);
    c3 += fn * bf_hi(u.y);
  }
  const float sw = si[b * NSS + i];
  atomicAdd(&comb[(size_t)b * HH + hb + 0], sw * c0);
  atomicAdd(&comb[(size_t)b * HH + hb + 1], sw * c1);
  atomicAdd(&comb[(size_t)b * HH + hb + 2], sw * c2);
  atomicAdd(&comb[(size_t)b * HH + hb + 3], sw * c3);
}

// ---------------------------------------------------------------------------
extern "C" void kernel_launch(void* const* d_in, const int* in_sizes, int n_in,
                              void* d_out, int out_size, void* d_ws, size_t ws_size,
                              hipStream_t stream) {
  (void)in_sizes; (void)n_in; (void)out_size; (void)ws_size;
  const float* x  = (const float*)d_in[0];
  const float* Wq = (const float*)d_in[1];
  const float* bq = (const float*)d_in[2];
  const float* Wk = (const float*)d_in[3];
  // d_in[4] = bk: provably unused (constant shift inside softmax)
  const float* Wv = (const float*)d_in[5];
  const float* bv = (const float*)d_in[6];
  const float* Wp = (const float*)d_in[7];
  const float* bp = (const float*)d_in[8];
  const float* Ws = (const float*)d_in[9];
  const float* bs = (const float*)d_in[10];
  const float* Wo = (const float*)d_in[11];
  const float* bo = (const float*)d_in[12];
  float* out = (float*)d_out;
  char* ws = (char*)d_ws;

  const size_t P_BYTES   = (size_t)32640 * HH * 2;   // 66,846,720
  const size_t WPT_BYTES = (size_t)NSS * HH * HH * 2; // 16,777,216
  uint16_t* P    = (uint16_t*)ws;                     // packed layout
  uint16_t* feat = (uint16_t*)(ws + P_BYTES);         // row-major
  uint16_t* Wpk  = (uint16_t*)(ws + 2 * P_BYTES);     // packed layout
  float* q    = (float*)(ws + 2 * P_BYTES + WPT_BYTES);
  float* qk   = q    + (size_t)BB * HH;
  float* comb = qk   + (size_t)BB * HH;
  float* D    = comb + (size_t)BB * HH;
  float* attn = D    + (size_t)BB * HH;
  float* xa   = attn + (size_t)BB * SS;
  float* si   = xa   + (size_t)BB * HH;
  float* l    = si   + (size_t)BB * NSS;

  // zero atomic-accumulated buffers (q, qk, comb, D are contiguous) + d_out
  hipMemsetAsync(q, 0, (size_t)4 * BB * HH * sizeof(float), stream);
  hipMemsetAsync(d_out, 0, (size_t)BB * HH * sizeof(float), stream);

  // Wp -> bf16 packed [scale][col-tile][kb2][kq][col][j] for MFMA B-operand
  wcvt<<<dim3(32, 32, NSS), 256, 0, stream>>>(Wp, Wpk);
  // q = x_last @ Wq + bq
  gemm64<false><<<dim3(16, 4), 256, 0, stream>>>(x + (size_t)(SS - 1) * HH, (size_t)SS * HH, Wq, bq, nullptr, q);
  // scale_importance
  si_kernel<<<BB, 256, 0, stream>>>(x, Ws, bs, si);
  // qk = Wk @ q (per batch)  <=>  qk[b][i] = sum_j q[b][j]*Wk[i][j]
  gemm64<true><<<dim3(16, 4), 256, 0, stream>>>(q, (size_t)HH, Wk, nullptr, nullptr, qk);
  // attention logits over x, pass 1
  score_kernel<<<dim3(128, BB), 256, 0, stream>>>(x, qk, attn);
  softmax_s<<<BB, 256, 0, stream>>>(attn);
  // pooling hierarchy + attn-weighted x accumulation, pass 2
  pool_kernel<<<dim3(4, BB), 256, 0, stream>>>(x, attn, P, xa);
  // the big one: feat = tanh(P @ Wp^T + bp) via bf16 MFMA, packed operands
  feat_gemm<<<dim3(8, 255), 256, 0, stream>>>(P, Wpk, bp, feat);
  // fa logits, softmax+ctx+combine
  falogit_kernel<<<8032, 256, 0, stream>>>(feat, q, l);
  ctx_kernel<<<dim3(NSS, BB), 256, 0, stream>>>(feat, l, si, comb);
  // D = xa @ Wv + bv + combined   (= base_context + combined)
  gemm64<false><<<dim3(16, 4), 256, 0, stream>>>(xa, (size_t)HH, Wv, bv, comb, D);
  // out = D @ Wo + bo
  gemm64<false><<<dim3(16, 4), 256, 0, stream>>>(D, (size_t)HH, Wo, bo, nullptr, out);
}